// Round 4
// baseline (784.098 us; speedup 1.0000x reference)
//
#include <hip/hip_runtime.h>
#include <hip/hip_bf16.h>

// GraphConvNormRelu: y = einsum('bctu,puv,poc->botv', x, A*g, W) + sum_p b;
// train-mode BN over (B,T,V); relu; +x residual.  B=32, C=64, T=512, V=54, P=4.
//
// R6 structure (R5 + full-line burst stores + linear pass2):
//   k_pass1 : per block (b, 4 t):
//             stage  : x tile -> Xs[64][72] bf16, masked to exactly 54
//                      floats/row (lanes f2>=27 write zeros). Prefetch for
//                      t+1 issued after barrier B (drains at barrier C,
//                      hidden under step-2 MFMAs).
//             step 1 : Z[c][pv] = X[c][u] @ Ae[pv][u]^T -> Zt[v][p*64+c].
//             step 2 : D[v][o] = Zt[v][256] @ W2[o][256]^T; y -> Ys LDS.
//             coop   : barrier, then 432 lane-contiguous uint4 stores of the
//                      6912B slice -> every 64B line fully dirtied in one
//                      burst (R4/R5: 4B stores spread over the mi-loop under
//                      L2 thrash caused ~4.5x partial-line write traffic).
//   k_pass2 : one block per pass1 tile; ypre read as contiguous dwords,
//             x/out as float2 in 216B runs; (a,c) via LDS table + magic-div.
//   k_prep, k_finalize unchanged.

typedef __bf16 bf16_t;
typedef __bf16 bf16x8 __attribute__((ext_vector_type(8)));
typedef __bf16 bf16x4 __attribute__((ext_vector_type(4)));
typedef float  f32x4  __attribute__((ext_vector_type(4)));
typedef unsigned int uint32;

static __device__ __forceinline__ f32x4 mfma16(bf16x8 a, bf16x8 b, f32x4 c) {
  return __builtin_amdgcn_mfma_f32_16x16x32_bf16(a, b, c, 0, 0, 0);
}
static __device__ __forceinline__ uint32 pk2(float a, float b) {
  union { __bf16 h; unsigned short u; } ua, ub;
  ua.h = (__bf16)a; ub.h = (__bf16)b;
  return (uint32)ua.u | ((uint32)ub.u << 16);
}
static __device__ __forceinline__ float bflo(uint32 u) {
  union { uint32 u; float f; } r; r.u = u << 16; return r.f;
}
static __device__ __forceinline__ float bfhi(uint32 u) {
  union { uint32 u; float f; } r; r.u = u & 0xffff0000u; return r.f;
}

// ---------------- k_prep ----------------
__global__ __launch_bounds__(256) void k_prep(
    const float* __restrict__ A, const float* __restrict__ g,
    const float* __restrict__ W, const float* __restrict__ bias,
    bf16_t* __restrict__ W2, bf16_t* __restrict__ Ae,
    float* __restrict__ bsum, float* __restrict__ stats) {
  int i = blockIdx.x * 256 + threadIdx.x;
  if (i < 16384) {                       // W2[o][p*64+c] = W[p][o][c]
    int o = i >> 8, k = i & 255, p = k >> 6, c = k & 63;
    W2[i] = (bf16_t)W[p * 4096 + o * 64 + c];
  }
  if (i < 224 * 64) {                    // Ae[p*56+v][u] = A[p][u][v]*g[p][u][v]
    int pv = i >> 6, u = i & 63;
    int p = pv / 56, v = pv - p * 56;
    float val = 0.f;
    if (v < 54 && u < 54) {
      int idx = (p * 54 + u) * 54 + v;
      val = A[idx] * g[idx];
    }
    Ae[i] = (bf16_t)val;
  }
  if (i < 64) {
    float s = 0.f;
    for (int p = 0; p < 4; ++p) s += bias[p * 64 + i];
    bsum[i] = s;
  }
  if (i < 8192) stats[i] = 0.f;
}

// ---------------- k_pass1 ----------------
#define ZS  264   // Zt row stride bf16: 132 dwords, gcd(132,32)=4 -> <=2-way banks
#define XSS 72    // Xs row stride bf16: 36 dwords == 4 mod 32 -> staggered banks

template<bool YBF16>
__global__ __launch_bounds__(256, 3) void k_pass1(
    const float* __restrict__ x, const bf16_t* __restrict__ W2,
    const bf16_t* __restrict__ Ae, const float* __restrict__ bsum,
    void* __restrict__ yprev, float* __restrict__ stats) {
  __shared__ bf16_t Zt[64 * ZS];                    // 33792 B
  __shared__ bf16_t Xs[64 * XSS];                   //  9216 B
  __shared__ __align__(16) bf16_t Ys[64 * 54];      //  6912 B (49920 total -> 3/CU)

  const int tid  = threadIdx.x;
  const int bid  = blockIdx.x;
  const int b    = bid >> 7;
  const int t0   = (bid & 127) << 2;
  const int w    = tid >> 6;
  const int L    = tid & 63;
  const int quad = L >> 4;
  const int l15  = L & 15;

  // zero Zt pad rows 56..63 once (rows 54/55 written zeros every t via Ae pad)
  for (int i = tid; i < 8 * ZS / 2; i += 256)
    ((uint32*)(Zt + 56 * ZS))[i] = 0u;

  // persistent step-2 B-frags: W2 row o = w*16+l15, k = kk*32+quad*8
  bf16x8 wf[8];
  #pragma unroll
  for (int kk = 0; kk < 8; ++kk)
    wf[kk] = *(const bf16x8*)(W2 + (((w << 4) + l15) << 8) + (kk << 5) + (quad << 3));

  // step-1 scatter offsets: col pv = n*16+l15 -> Zt[v][p*64 + c0]
  int zoff[14];
  #pragma unroll
  for (int n = 0; n < 14; ++n) {
    int pv = (n << 4) + l15;
    int p = pv / 56;
    int v = pv - p * 56;
    zoff[n] = v * ZS + (p << 6) + (w << 4) + (quad << 2);
  }

  const int oc  = (w << 4) + l15;      // step-2 output channel; step-1 c-row
  const float bsv = bsum[oc];
  float ssum = 0.f, ssq = 0.f;

  // ---- staging geometry: thread covers (c = (tid>>5) + 8j, f2 = tid&31) ----
  const int  f2   = tid & 31;
  const bool ldon = f2 < 27;           // exactly 54 floats/row; rest zero-pad
  const size_t gbase = ((size_t)(b << 6) + (tid >> 5)) * 27648 + ((size_t)f2 << 1);
  uint32* xsd = (uint32*)((char*)Xs + (tid >> 5) * (XSS * 2) + (f2 << 2));

  float2 pf[8];
  #pragma unroll
  for (int j = 0; j < 8; ++j) pf[j] = make_float2(0.f, 0.f);
  if (ldon) {
    #pragma unroll
    for (int j = 0; j < 8; ++j)
      pf[j] = *(const float2*)(x + gbase + (size_t)j * 221184 + (size_t)t0 * 54);
  }

  for (int tt = 0; tt < 4; ++tt) {
    const int t = t0 + tt;

    // write staged tile (bf16 pairs; zero pad cols 54..63)
    #pragma unroll
    for (int j = 0; j < 8; ++j) xsd[j * 288] = pk2(pf[j].x, pf[j].y);

    __syncthreads();   // [A] Xs ready; prev coop-store Ys reads complete

    // ---- step 1: Z[c][pv] = X[c][u] @ Ae[pv][u]^T ----
    const bf16_t* xr = Xs + oc * XSS;
    bf16x8 xa0 = *(const bf16x8*)(xr + (quad << 3));
    bf16x8 xa1 = *(const bf16x8*)(xr + 32 + (quad << 3));
    #pragma unroll
    for (int n = 0; n < 14; ++n) {
      const bf16_t* ar = Ae + (((n << 4) + l15) << 6) + (quad << 3);
      f32x4 acc = {0.f, 0.f, 0.f, 0.f};
      acc = mfma16(xa0, *(const bf16x8*)(ar), acc);
      acc = mfma16(xa1, *(const bf16x8*)(ar + 32), acc);
      uint32* dst = (uint32*)(Zt + zoff[n]);
      dst[0] = pk2(acc[0], acc[1]);
      dst[1] = pk2(acc[2], acc[3]);
    }

    __syncthreads();   // [B] Zt ready

    // prefetch next t (drains at barrier C, hidden under step-2 MFMAs)
    if (ldon && tt < 3) {
      #pragma unroll
      for (int j = 0; j < 8; ++j)
        pf[j] = *(const float2*)(x + gbase + (size_t)j * 221184 + (size_t)(t + 1) * 54);
    }

    // ---- step 2: D[v][o] = Zt[v][K] @ W2[o][K]^T ----
    const size_t obase = (((size_t)((b << 6) + oc) << 9) + (size_t)t) * 54;
    #pragma unroll
    for (int mi = 0; mi < 4; ++mi) {
      f32x4 acc = {0.f, 0.f, 0.f, 0.f};
      #pragma unroll
      for (int kk = 0; kk < 8; ++kk) {
        bf16x8 za = *(const bf16x8*)(Zt + ((mi << 4) + l15) * ZS
                                        + (kk << 5) + (quad << 3));
        acc = mfma16(za, wf[kk], acc);
      }
      const int v0 = (mi << 4) + (quad << 2);
      if (v0 + 3 < 54) {
        float y0 = acc[0] + bsv, y1 = acc[1] + bsv, y2 = acc[2] + bsv, y3 = acc[3] + bsv;
        if (YBF16) {
          uint32* d = (uint32*)(Ys + oc * 54 + v0);
          d[0] = pk2(y0, y1); d[1] = pk2(y2, y3);
        } else {
          float2* d = (float2*)((float*)yprev + obase + v0);
          d[0] = make_float2(y0, y1); d[1] = make_float2(y2, y3);
        }
        ssum += y0 + y1 + y2 + y3;
        ssq  += y0 * y0 + y1 * y1 + y2 * y2 + y3 * y3;
      } else if (v0 == 52) {
        float y0 = acc[0] + bsv, y1 = acc[1] + bsv;
        if (YBF16) {
          *(uint32*)(Ys + oc * 54 + v0) = pk2(y0, y1);
        } else {
          *(float2*)((float*)yprev + obase + v0) = make_float2(y0, y1);
        }
        ssum += y0 + y1;
        ssq  += y0 * y0 + y1 * y1;
      }
    }

    if (YBF16) {
      __syncthreads();   // [C] Ys complete; prefetch landed
      // cooperative full-line store: yblk[bid][tt] slice = 432 x uint4
      const uint4* ys4 = (const uint4*)Ys;
      uint4* yp4 = (uint4*)((uint32*)yprev + (size_t)bid * 6912 + (size_t)tt * 1728);
      yp4[tid] = ys4[tid];
      if (tid < 176) yp4[256 + tid] = ys4[256 + tid];
    } else {
      __syncthreads();   // [C] keep barrier structure identical
    }
  }

  // reduce stats across the 4 quads holding the same channel
  ssum += __shfl_xor(ssum, 16); ssq += __shfl_xor(ssq, 16);
  ssum += __shfl_xor(ssum, 32); ssq += __shfl_xor(ssq, 32);
  if (L < 16) {
    float* sb = stats + (bid & 63) * 128;
    atomicAdd(&sb[oc], ssum);
    atomicAdd(&sb[64 + oc], ssq);
  }
}

// ---------------- k_finalize ----------------
__global__ void k_finalize(const float* __restrict__ gamma, const float* __restrict__ beta,
                           const float* __restrict__ stats, float* __restrict__ ac) {
  int o = threadIdx.x;
  if (o >= 64) return;
  float S = 0.f, Q = 0.f;
  for (int buf = 0; buf < 64; ++buf) {
    S += stats[buf * 128 + o];
    Q += stats[buf * 128 + 64 + o];
  }
  const float inv = 1.0f / 884736.0f;
  float mean = S * inv;
  float var  = Q * inv - mean * mean;
  float a = gamma[o] * rsqrtf(var + 1e-5f);
  ac[o] = a;
  ac[64 + o] = beta[o] - mean * a;
}

// ---------------- k_pass2 (linear, yblk layout) ----------------
__global__ __launch_bounds__(256) void k_pass2_lin(
    const float* __restrict__ x, const float* __restrict__ ac,
    const void* __restrict__ yprev, float* __restrict__ out) {
  __shared__ float acS[128];
  const int tid = threadIdx.x;
  const int bid = blockIdx.x;
  if (tid < 128) acS[tid] = ac[tid];
  __syncthreads();

  const int b  = bid >> 7;
  const int t0 = (bid & 127) << 2;
  const uint32* yp = (const uint32*)yprev + (size_t)bid * 6912;
  const float* xb  = x + (size_t)b * 1769472;
  float* ob        = out + (size_t)b * 1769472;

  #pragma unroll 3
  for (int k = 0; k < 27; ++k) {
    const int d  = (k << 8) + tid;       // dword index, < 6912
    const int e0 = d << 1;               // bf16 element index (even)
    const unsigned tt = (unsigned)e0 / 3456u;
    const unsigned r  = (unsigned)e0 - tt * 3456u;
    const unsigned ocv = r / 54u;
    const unsigned v   = r - ocv * 54u;
    const uint32 u = yp[d];
    const float a = acS[ocv], cc = acS[64 + ocv];
    const size_t xi = (size_t)ocv * 27648 + (size_t)(t0 + tt) * 54 + v;
    const float2 xv = *(const float2*)(xb + xi);
    float2 o2;
    o2.x = fmaxf(fmaf(a, bflo(u), cc), 0.f) + xv.x;
    o2.y = fmaxf(fmaf(a, bfhi(u), cc), 0.f) + xv.y;
    *(float2*)(ob + xi) = o2;
  }
}

// ---------------- k_pass2 fallback (legacy linear fp32 in d_out) ----------------
__global__ __launch_bounds__(256) void k_pass2_fb(const float* __restrict__ x,
                                                  const float* __restrict__ ac,
                                                  const float* __restrict__ yprev,
                                                  float* __restrict__ out) {
  const int slab = blockIdx.y;
  const int o = slab & 63;
  const size_t base = (size_t)slab * 27648 + (size_t)(((blockIdx.x << 8) + threadIdx.x) << 2);
  const float a = ac[o], c = ac[64 + o];
  float4 yp = *(const float4*)(yprev + base);
  float4 xv = *(const float4*)(x + base);
  float4 r;
  r.x = fmaxf(fmaf(a, yp.x, c), 0.f) + xv.x;
  r.y = fmaxf(fmaf(a, yp.y, c), 0.f) + xv.y;
  r.z = fmaxf(fmaf(a, yp.z, c), 0.f) + xv.z;
  r.w = fmaxf(fmaf(a, yp.w, c), 0.f) + xv.w;
  *(float4*)(out + base) = r;
}

extern "C" void kernel_launch(void* const* d_in, const int* in_sizes, int n_in,
                              void* d_out, int out_size, void* d_ws, size_t ws_size,
                              hipStream_t stream) {
  const float* x     = (const float*)d_in[0];
  const float* A     = (const float*)d_in[1];
  const float* g     = (const float*)d_in[2];
  const float* W     = (const float*)d_in[3];
  const float* bias  = (const float*)d_in[4];
  const float* gamma = (const float*)d_in[5];
  const float* beta  = (const float*)d_in[6];

  char* ws = (char*)d_ws;
  bf16_t* W2    = (bf16_t*)(ws + 0);       // 32768 B
  bf16_t* Ae    = (bf16_t*)(ws + 32768);   // 28672 B
  float*  bsum  = (float*)(ws + 61440);    // 256 B
  float*  stats = (float*)(ws + 61696);    // 32768 B
  float*  ac    = (float*)(ws + 94464);    // 512 B
  const size_t YP_OFF   = 98304;
  const size_t YP_BYTES = (size_t)32 * 64 * 512 * 54 * 2;   // 113246208
  float* out = (float*)d_out;

  k_prep<<<64, 256, 0, stream>>>(A, g, W, bias, W2, Ae, bsum, stats);

  if (ws_size >= YP_OFF + YP_BYTES + 4096) {
    bf16_t* ypre = (bf16_t*)(ws + YP_OFF);
    k_pass1<true><<<4096, 256, 0, stream>>>(x, W2, Ae, bsum, ypre, stats);
    k_finalize<<<1, 64, 0, stream>>>(gamma, beta, stats, ac);
    k_pass2_lin<<<4096, 256, 0, stream>>>(x, ac, ypre, out);
  } else {
    // fallback: fp32 ypre staged in d_out (legacy layout), pass2 in place
    k_pass1<false><<<4096, 256, 0, stream>>>(x, W2, Ae, bsum, out, stats);
    k_finalize<<<1, 64, 0, stream>>>(gamma, beta, stats, ac);
    k_pass2_fb<<<dim3(27, 2048), 256, 0, stream>>>(x, ac, out, out);
  }
}

// Round 6
// 717.763 us; speedup vs baseline: 1.0924x; 1.0924x over previous
//
#include <hip/hip_runtime.h>
#include <hip/hip_bf16.h>

// GraphConvNormRelu: y = einsum('bctu,puv,poc->botv', x, A*g, W) + sum_p b;
// train-mode BN over (B,T,V); relu; +x residual.  B=32, C=64, T=512, V=54, P=4.
//
// R7 structure (R6 + bf16 pre-cast of x -> L3-warm pass1 input):
//   Empirics R2 vs R4-R6: pass1 shows clean HBM write traffic (118MB for a
//   113MB ypre) ONLY when its input stream is a 113MB bf16 buffer that is
//   L3-resident; streaming 226MB cold fp32 x puts the kernel in an L3-thrash
//   regime with ~2-4.5x FETCH/WRITE amplification that is invariant to the
//   store pattern (R4 scattered / R5 blocked / R6 full-line-burst all ~510MB).
//   Fix: k_cast streams x fp32 -> xbf bf16 once (pure coalesced copy); pass1
//   stages from xbf (L3-warm, natural order - no transpose needed with the
//   u-first contraction).
//   k_pass1_bf : per block (b, 4 t):
//     stage  : xbf tile -> Xs[64][72], 1 dword/lane, masked 27 lanes/row.
//     step 1 : Z[c][pv] = X[c][u] @ Ae[pv][u]^T -> Zt[v][p*64+c]  (LDS).
//     step 2 : D[v][o] = Zt[v][256] @ W2[o][256]^T -> Ys LDS.
//     coop   : 432 lane-contiguous uint4 stores of the 6912B yblk slice.
//   k_pass2_lin : linear dword reads of yblk, float2 x/out, (a,c) LDS table.
//   k_prep, k_finalize unchanged; legacy fp32 fallback retained.
//
// (Resubmission of R7 verbatim: previous round failed with an MI355X
//  container acquisition error before the kernel ever ran.)

typedef __bf16 bf16_t;
typedef __bf16 bf16x8 __attribute__((ext_vector_type(8)));
typedef __bf16 bf16x4 __attribute__((ext_vector_type(4)));
typedef float  f32x4  __attribute__((ext_vector_type(4)));
typedef unsigned int uint32;

static __device__ __forceinline__ f32x4 mfma16(bf16x8 a, bf16x8 b, f32x4 c) {
  return __builtin_amdgcn_mfma_f32_16x16x32_bf16(a, b, c, 0, 0, 0);
}
static __device__ __forceinline__ uint32 pk2(float a, float b) {
  union { __bf16 h; unsigned short u; } ua, ub;
  ua.h = (__bf16)a; ub.h = (__bf16)b;
  return (uint32)ua.u | ((uint32)ub.u << 16);
}
static __device__ __forceinline__ float bflo(uint32 u) {
  union { uint32 u; float f; } r; r.u = u << 16; return r.f;
}
static __device__ __forceinline__ float bfhi(uint32 u) {
  union { uint32 u; float f; } r; r.u = u & 0xffff0000u; return r.f;
}

// ---------------- k_prep ----------------
__global__ __launch_bounds__(256) void k_prep(
    const float* __restrict__ A, const float* __restrict__ g,
    const float* __restrict__ W, const float* __restrict__ bias,
    bf16_t* __restrict__ W2, bf16_t* __restrict__ Ae,
    float* __restrict__ bsum, float* __restrict__ stats) {
  int i = blockIdx.x * 256 + threadIdx.x;
  if (i < 16384) {                       // W2[o][p*64+c] = W[p][o][c]
    int o = i >> 8, k = i & 255, p = k >> 6, c = k & 63;
    W2[i] = (bf16_t)W[p * 4096 + o * 64 + c];
  }
  if (i < 224 * 64) {                    // Ae[p*56+v][u] = A[p][u][v]*g[p][u][v]
    int pv = i >> 6, u = i & 63;
    int p = pv / 56, v = pv - p * 56;
    float val = 0.f;
    if (v < 54 && u < 54) {
      int idx = (p * 54 + u) * 54 + v;
      val = A[idx] * g[idx];
    }
    Ae[i] = (bf16_t)val;
  }
  if (i < 64) {
    float s = 0.f;
    for (int p = 0; p < 4; ++p) s += bias[p * 64 + i];
    bsum[i] = s;
  }
  if (i < 8192) stats[i] = 0.f;
}

// ---------------- k_cast : x fp32 -> xbf bf16, pure stream ----------------
__global__ __launch_bounds__(256) void k_cast(const float* __restrict__ x,
                                              bf16_t* __restrict__ xbf) {
  const size_t i = (size_t)blockIdx.x * 256 + threadIdx.x;   // 27648 blocks
  const float4 a = ((const float4*)x)[2 * i];
  const float4 b = ((const float4*)x)[2 * i + 1];
  union { uint32 u[4]; uint4 v; } r;
  r.u[0] = pk2(a.x, a.y); r.u[1] = pk2(a.z, a.w);
  r.u[2] = pk2(b.x, b.y); r.u[3] = pk2(b.z, b.w);
  ((uint4*)xbf)[i] = r.v;
}

// ---------------- k_pass1_bf (primary) ----------------
#define ZS  264   // Zt row stride bf16: 132 dwords, gcd(132,32)=4 -> <=2-way banks
#define XSS 72    // Xs row stride bf16: 36 dwords == 4 mod 32 -> staggered banks

__global__ __launch_bounds__(256, 3) void k_pass1_bf(
    const bf16_t* __restrict__ xbf, const bf16_t* __restrict__ W2,
    const bf16_t* __restrict__ Ae, const float* __restrict__ bsum,
    bf16_t* __restrict__ yprev, float* __restrict__ stats) {
  __shared__ bf16_t Zt[64 * ZS];                    // 33792 B
  __shared__ bf16_t Xs[64 * XSS];                   //  9216 B
  __shared__ __align__(16) bf16_t Ys[64 * 54];      //  6912 B (49920 -> 3/CU)

  const int tid  = threadIdx.x;
  const int bid  = blockIdx.x;
  const int b    = bid >> 7;
  const int t0   = (bid & 127) << 2;
  const int w    = tid >> 6;
  const int L    = tid & 63;
  const int quad = L >> 4;
  const int l15  = L & 15;

  // zero Zt pad rows 56..63 once (rows 54/55 written zeros every t via Ae pad)
  for (int i = tid; i < 8 * ZS / 2; i += 256)
    ((uint32*)(Zt + 56 * ZS))[i] = 0u;

  // persistent step-2 B-frags: W2 row o = w*16+l15, k = kk*32+quad*8
  bf16x8 wf[8];
  #pragma unroll
  for (int kk = 0; kk < 8; ++kk)
    wf[kk] = *(const bf16x8*)(W2 + (((w << 4) + l15) << 8) + (kk << 5) + (quad << 3));

  // step-1 scatter offsets: col pv = n*16+l15 -> Zt[v][p*64 + c0]
  int zoff[14];
  #pragma unroll
  for (int n = 0; n < 14; ++n) {
    int pv = (n << 4) + l15;
    int p = pv / 56;
    int v = pv - p * 56;
    zoff[n] = v * ZS + (p << 6) + (w << 4) + (quad << 2);
  }

  const int oc  = (w << 4) + l15;      // step-2 output channel; step-1 c-row
  const float bsv = bsum[oc];
  float ssum = 0.f, ssq = 0.f;

  // ---- staging geometry: thread covers (c = (tid>>5) + 8j, f2 = tid&31) ----
  // xbf row (c,t) = 54 bf16 = 27 dwords; lanes f2<27 each load 1 dword.
  const int  f2   = tid & 31;
  const bool ldon = f2 < 27;
  const bf16_t* xgb = xbf + ((size_t)(b << 6) + (tid >> 5)) * 27648 + (f2 << 1);
  uint32* xsd = (uint32*)((char*)Xs + (tid >> 5) * (XSS * 2) + (f2 << 2));

  uint32 pfu[8];
  #pragma unroll
  for (int j = 0; j < 8; ++j) pfu[j] = 0u;
  if (ldon) {
    #pragma unroll
    for (int j = 0; j < 8; ++j)
      pfu[j] = *(const uint32*)(xgb + (size_t)j * 221184 + (size_t)t0 * 54);
  }

  for (int tt = 0; tt < 4; ++tt) {
    const int t = t0 + tt;

    // write staged tile (zero pad cols 54..63 via masked lanes' zeros)
    #pragma unroll
    for (int j = 0; j < 8; ++j) xsd[j * 288] = pfu[j];

    __syncthreads();   // [A] Xs ready; prev coop-store Ys reads complete

    // ---- step 1: Z[c][pv] = X[c][u] @ Ae[pv][u]^T ----
    const bf16_t* xr = Xs + oc * XSS;
    bf16x8 xa0 = *(const bf16x8*)(xr + (quad << 3));
    bf16x8 xa1 = *(const bf16x8*)(xr + 32 + (quad << 3));
    #pragma unroll
    for (int n = 0; n < 14; ++n) {
      const bf16_t* ar = Ae + (((n << 4) + l15) << 6) + (quad << 3);
      f32x4 acc = {0.f, 0.f, 0.f, 0.f};
      acc = mfma16(xa0, *(const bf16x8*)(ar), acc);
      acc = mfma16(xa1, *(const bf16x8*)(ar + 32), acc);
      uint32* dst = (uint32*)(Zt + zoff[n]);
      dst[0] = pk2(acc[0], acc[1]);
      dst[1] = pk2(acc[2], acc[3]);
    }

    __syncthreads();   // [B] Zt ready

    // prefetch next t (drains at barrier C, hidden under step-2 MFMAs)
    if (ldon && tt < 3) {
      #pragma unroll
      for (int j = 0; j < 8; ++j)
        pfu[j] = *(const uint32*)(xgb + (size_t)j * 221184 + (size_t)(t + 1) * 54);
    }

    // ---- step 2: D[v][o] = Zt[v][K] @ W2[o][K]^T -> Ys ----
    #pragma unroll
    for (int mi = 0; mi < 4; ++mi) {
      f32x4 acc = {0.f, 0.f, 0.f, 0.f};
      #pragma unroll
      for (int kk = 0; kk < 8; ++kk) {
        bf16x8 za = *(const bf16x8*)(Zt + ((mi << 4) + l15) * ZS
                                        + (kk << 5) + (quad << 3));
        acc = mfma16(za, wf[kk], acc);
      }
      const int v0 = (mi << 4) + (quad << 2);
      if (v0 + 3 < 54) {
        float y0 = acc[0] + bsv, y1 = acc[1] + bsv, y2 = acc[2] + bsv, y3 = acc[3] + bsv;
        uint32* d = (uint32*)(Ys + oc * 54 + v0);
        d[0] = pk2(y0, y1); d[1] = pk2(y2, y3);
        ssum += y0 + y1 + y2 + y3;
        ssq  += y0 * y0 + y1 * y1 + y2 * y2 + y3 * y3;
      } else if (v0 == 52) {
        float y0 = acc[0] + bsv, y1 = acc[1] + bsv;
        *(uint32*)(Ys + oc * 54 + v0) = pk2(y0, y1);
        ssum += y0 + y1;
        ssq  += y0 * y0 + y1 * y1;
      }
    }

    __syncthreads();   // [C] Ys complete; prefetch landed
    // cooperative full-line store: yblk[bid][tt] slice = 432 x uint4
    const uint4* ys4 = (const uint4*)Ys;
    uint4* yp4 = (uint4*)((uint32*)yprev + (size_t)bid * 6912 + (size_t)tt * 1728);
    yp4[tid] = ys4[tid];
    if (tid < 176) yp4[256 + tid] = ys4[256 + tid];
  }

  // reduce stats across the 4 quads holding the same channel
  ssum += __shfl_xor(ssum, 16); ssq += __shfl_xor(ssq, 16);
  ssum += __shfl_xor(ssum, 32); ssq += __shfl_xor(ssq, 32);
  if (L < 16) {
    float* sb = stats + (bid & 63) * 128;
    atomicAdd(&sb[oc], ssum);
    atomicAdd(&sb[64 + oc], ssq);
  }
}

// ---------------- k_pass1_fp32 (fallback: fp32 x in, fp32 ypre to d_out) ----
__global__ __launch_bounds__(256, 3) void k_pass1_fp32(
    const float* __restrict__ x, const bf16_t* __restrict__ W2,
    const bf16_t* __restrict__ Ae, const float* __restrict__ bsum,
    float* __restrict__ yprev, float* __restrict__ stats) {
  __shared__ bf16_t Zt[64 * ZS];
  __shared__ bf16_t Xs[64 * XSS];

  const int tid  = threadIdx.x;
  const int bid  = blockIdx.x;
  const int b    = bid >> 7;
  const int t0   = (bid & 127) << 2;
  const int w    = tid >> 6;
  const int L    = tid & 63;
  const int quad = L >> 4;
  const int l15  = L & 15;

  for (int i = tid; i < 8 * ZS / 2; i += 256)
    ((uint32*)(Zt + 56 * ZS))[i] = 0u;

  bf16x8 wf[8];
  #pragma unroll
  for (int kk = 0; kk < 8; ++kk)
    wf[kk] = *(const bf16x8*)(W2 + (((w << 4) + l15) << 8) + (kk << 5) + (quad << 3));

  int zoff[14];
  #pragma unroll
  for (int n = 0; n < 14; ++n) {
    int pv = (n << 4) + l15;
    int p = pv / 56;
    int v = pv - p * 56;
    zoff[n] = v * ZS + (p << 6) + (w << 4) + (quad << 2);
  }

  const int oc  = (w << 4) + l15;
  const float bsv = bsum[oc];
  float ssum = 0.f, ssq = 0.f;

  const int  f2   = tid & 31;
  const bool ldon = f2 < 27;
  const size_t gbase = ((size_t)(b << 6) + (tid >> 5)) * 27648 + ((size_t)f2 << 1);
  uint32* xsd = (uint32*)((char*)Xs + (tid >> 5) * (XSS * 2) + (f2 << 2));

  float2 pf[8];
  #pragma unroll
  for (int j = 0; j < 8; ++j) pf[j] = make_float2(0.f, 0.f);
  if (ldon) {
    #pragma unroll
    for (int j = 0; j < 8; ++j)
      pf[j] = *(const float2*)(x + gbase + (size_t)j * 221184 + (size_t)t0 * 54);
  }

  for (int tt = 0; tt < 4; ++tt) {
    const int t = t0 + tt;
    #pragma unroll
    for (int j = 0; j < 8; ++j) xsd[j * 288] = pk2(pf[j].x, pf[j].y);
    __syncthreads();

    const bf16_t* xr = Xs + oc * XSS;
    bf16x8 xa0 = *(const bf16x8*)(xr + (quad << 3));
    bf16x8 xa1 = *(const bf16x8*)(xr + 32 + (quad << 3));
    #pragma unroll
    for (int n = 0; n < 14; ++n) {
      const bf16_t* ar = Ae + (((n << 4) + l15) << 6) + (quad << 3);
      f32x4 acc = {0.f, 0.f, 0.f, 0.f};
      acc = mfma16(xa0, *(const bf16x8*)(ar), acc);
      acc = mfma16(xa1, *(const bf16x8*)(ar + 32), acc);
      uint32* dst = (uint32*)(Zt + zoff[n]);
      dst[0] = pk2(acc[0], acc[1]);
      dst[1] = pk2(acc[2], acc[3]);
    }
    __syncthreads();

    if (ldon && tt < 3) {
      #pragma unroll
      for (int j = 0; j < 8; ++j)
        pf[j] = *(const float2*)(x + gbase + (size_t)j * 221184 + (size_t)(t + 1) * 54);
    }

    const size_t obase = (((size_t)((b << 6) + oc) << 9) + (size_t)t) * 54;
    #pragma unroll
    for (int mi = 0; mi < 4; ++mi) {
      f32x4 acc = {0.f, 0.f, 0.f, 0.f};
      #pragma unroll
      for (int kk = 0; kk < 8; ++kk) {
        bf16x8 za = *(const bf16x8*)(Zt + ((mi << 4) + l15) * ZS
                                        + (kk << 5) + (quad << 3));
        acc = mfma16(za, wf[kk], acc);
      }
      const int v0 = (mi << 4) + (quad << 2);
      if (v0 + 3 < 54) {
        float y0 = acc[0] + bsv, y1 = acc[1] + bsv, y2 = acc[2] + bsv, y3 = acc[3] + bsv;
        float2* d = (float2*)(yprev + obase + v0);
        d[0] = make_float2(y0, y1); d[1] = make_float2(y2, y3);
        ssum += y0 + y1 + y2 + y3;
        ssq  += y0 * y0 + y1 * y1 + y2 * y2 + y3 * y3;
      } else if (v0 == 52) {
        float y0 = acc[0] + bsv, y1 = acc[1] + bsv;
        *(float2*)(yprev + obase + v0) = make_float2(y0, y1);
        ssum += y0 + y1;
        ssq  += y0 * y0 + y1 * y1;
      }
    }
    __syncthreads();
  }

  ssum += __shfl_xor(ssum, 16); ssq += __shfl_xor(ssq, 16);
  ssum += __shfl_xor(ssum, 32); ssq += __shfl_xor(ssq, 32);
  if (L < 16) {
    float* sb = stats + (bid & 63) * 128;
    atomicAdd(&sb[oc], ssum);
    atomicAdd(&sb[64 + oc], ssq);
  }
}

// ---------------- k_finalize ----------------
__global__ void k_finalize(const float* __restrict__ gamma, const float* __restrict__ beta,
                           const float* __restrict__ stats, float* __restrict__ ac) {
  int o = threadIdx.x;
  if (o >= 64) return;
  float S = 0.f, Q = 0.f;
  for (int buf = 0; buf < 64; ++buf) {
    S += stats[buf * 128 + o];
    Q += stats[buf * 128 + 64 + o];
  }
  const float inv = 1.0f / 884736.0f;
  float mean = S * inv;
  float var  = Q * inv - mean * mean;
  float a = gamma[o] * rsqrtf(var + 1e-5f);
  ac[o] = a;
  ac[64 + o] = beta[o] - mean * a;
}

// ---------------- k_pass2 (linear, yblk layout) ----------------
__global__ __launch_bounds__(256) void k_pass2_lin(
    const float* __restrict__ x, const float* __restrict__ ac,
    const void* __restrict__ yprev, float* __restrict__ out) {
  __shared__ float acS[128];
  const int tid = threadIdx.x;
  const int bid = blockIdx.x;
  if (tid < 128) acS[tid] = ac[tid];
  __syncthreads();

  const int b  = bid >> 7;
  const int t0 = (bid & 127) << 2;
  const uint32* yp = (const uint32*)yprev + (size_t)bid * 6912;
  const float* xb  = x + (size_t)b * 1769472;
  float* ob        = out + (size_t)b * 1769472;

  #pragma unroll 3
  for (int k = 0; k < 27; ++k) {
    const int d  = (k << 8) + tid;       // dword index, < 6912
    const int e0 = d << 1;               // bf16 element index (even)
    const unsigned tt = (unsigned)e0 / 3456u;
    const unsigned r  = (unsigned)e0 - tt * 3456u;
    const unsigned ocv = r / 54u;
    const unsigned v   = r - ocv * 54u;
    const uint32 u = yp[d];
    const float a = acS[ocv], cc = acS[64 + ocv];
    const size_t xi = (size_t)ocv * 27648 + (size_t)(t0 + tt) * 54 + v;
    const float2 xv = *(const float2*)(xb + xi);
    float2 o2;
    o2.x = fmaxf(fmaf(a, bflo(u), cc), 0.f) + xv.x;
    o2.y = fmaxf(fmaf(a, bfhi(u), cc), 0.f) + xv.y;
    *(float2*)(ob + xi) = o2;
  }
}

// ---------------- k_pass2 fallback (legacy linear fp32 in d_out) ----------------
__global__ __launch_bounds__(256) void k_pass2_fb(const float* __restrict__ x,
                                                  const float* __restrict__ ac,
                                                  const float* __restrict__ yprev,
                                                  float* __restrict__ out) {
  const int slab = blockIdx.y;
  const int o = slab & 63;
  const size_t base = (size_t)slab * 27648 + (size_t)(((blockIdx.x << 8) + threadIdx.x) << 2);
  const float a = ac[o], c = ac[64 + o];
  float4 yp = *(const float4*)(yprev + base);
  float4 xv = *(const float4*)(x + base);
  float4 r;
  r.x = fmaxf(fmaf(a, yp.x, c), 0.f) + xv.x;
  r.y = fmaxf(fmaf(a, yp.y, c), 0.f) + xv.y;
  r.z = fmaxf(fmaf(a, yp.z, c), 0.f) + xv.z;
  r.w = fmaxf(fmaf(a, yp.w, c), 0.f) + xv.w;
  *(float4*)(out + base) = r;
}

extern "C" void kernel_launch(void* const* d_in, const int* in_sizes, int n_in,
                              void* d_out, int out_size, void* d_ws, size_t ws_size,
                              hipStream_t stream) {
  const float* x     = (const float*)d_in[0];
  const float* A     = (const float*)d_in[1];
  const float* g     = (const float*)d_in[2];
  const float* W     = (const float*)d_in[3];
  const float* bias  = (const float*)d_in[4];
  const float* gamma = (const float*)d_in[5];
  const float* beta  = (const float*)d_in[6];

  char* ws = (char*)d_ws;
  bf16_t* W2    = (bf16_t*)(ws + 0);       // 32768 B
  bf16_t* Ae    = (bf16_t*)(ws + 32768);   // 28672 B
  float*  bsum  = (float*)(ws + 61440);    // 256 B
  float*  stats = (float*)(ws + 61696);    // 32768 B
  float*  ac    = (float*)(ws + 94464);    // 512 B
  const size_t XBF_OFF   = 98304;
  const size_t XBF_BYTES = (size_t)32 * 64 * 512 * 54 * 2;   // 113246208
  const size_t YP_OFF    = XBF_OFF + XBF_BYTES;              // 113344512
  float* out = (float*)d_out;

  k_prep<<<64, 256, 0, stream>>>(A, g, W, bias, W2, Ae, bsum, stats);

  if (ws_size >= YP_OFF + XBF_BYTES + 4096) {
    bf16_t* xbf  = (bf16_t*)(ws + XBF_OFF);
    bf16_t* ypre = (bf16_t*)(ws + YP_OFF);
    k_cast<<<27648, 256, 0, stream>>>(x, xbf);
    k_pass1_bf<<<4096, 256, 0, stream>>>(xbf, W2, Ae, bsum, ypre, stats);
    k_finalize<<<1, 64, 0, stream>>>(gamma, beta, stats, ac);
    k_pass2_lin<<<4096, 256, 0, stream>>>(x, ac, ypre, out);
  } else {
    // fallback: fp32 ypre staged in d_out (legacy layout), pass2 in place
    k_pass1_fp32<<<4096, 256, 0, stream>>>(x, W2, Ae, bsum, out, stats);
    k_finalize<<<1, 64, 0, stream>>>(gamma, beta, stats, ac);
    k_pass2_fb<<<dim3(27, 2048), 256, 0, stream>>>(x, ac, out, out);
  }
}